// Round 1
// baseline (12734.406 us; speedup 1.0000x reference)
//
#include <hip/hip_runtime.h>
#include <cstdint>
#include <cstddef>

#define DIM 1024
#define NS 8
#define RANK 256
#define TSTEPS 1024
#define BB 8
#define NG 16      // workgroups per slot
#define RCH 16     // RANK / NG
#define DCH 64     // DIM / NG

typedef __attribute__((ext_vector_type(8))) short s8v;   // 8 x bf16 (A/B frag)
typedef __attribute__((ext_vector_type(4))) short s4v;   // 4 x bf16
typedef __attribute__((ext_vector_type(4))) float f4v;   // MFMA C/D frag

__device__ __forceinline__ unsigned short f2bf(float f) {
  unsigned u = __float_as_uint(f);
  u += 0x7fffu + ((u >> 16) & 1u);          // round-to-nearest-even
  return (unsigned short)(u >> 16);
}
__device__ __forceinline__ float bf2f(unsigned short h) {
  return __uint_as_float(((unsigned)h) << 16);
}

// ---------------------------------------------------------------- init ----
// Convert U,V to bf16 in ws; seed h exchange + h[t=0] output; zero counters.
__global__ void init_kernel(const float* __restrict__ U, const float* __restrict__ V,
                            const float* __restrict__ h0,
                            unsigned short* __restrict__ Ub, unsigned short* __restrict__ Vb,
                            unsigned short* __restrict__ hx, float* __restrict__ hOut0,
                            unsigned int* __restrict__ cnt) {
  const size_t NU = (size_t)NS * DIM * RANK;   // 2,097,152
  const size_t NH = (size_t)NS * BB * DIM;     // 65,536
  size_t i = (size_t)blockIdx.x * blockDim.x + threadIdx.x;
  const size_t total = 2 * NU + 2 * NH + 16;
  for (; i < total; i += (size_t)gridDim.x * blockDim.x) {
    if (i < NU) {
      Ub[i] = f2bf(U[i]);                       // [S][D][R] flat
    } else if (i < 2 * NU) {
      Vb[i - NU] = f2bf(V[i - NU]);             // [S][R][D] flat
    } else if (i < 2 * NU + NH) {
      size_t j = i - 2 * NU;                    // [s][b][d]
      int s = (int)(j >> 13), b = (int)((j >> 10) & 7), d = (int)(j & 1023);
      hx[((size_t)(s * 2 + 0) * BB + b) * DIM + d] =
          f2bf(h0[((size_t)b * NS + s) * DIM + d]);
    } else if (i < 2 * NU + 2 * NH) {
      size_t j = i - 2 * NU - NH;               // hOut[0][s][b][d]
      int s = (int)(j >> 13), b = (int)((j >> 10) & 7), d = (int)(j & 1023);
      hOut0[j] = h0[((size_t)b * NS + s) * DIM + d];
    } else {
      cnt[i - (2 * NU + 2 * NH)] = 0u;
    }
  }
}

// ---------------------------------------------------------------- GEMM ----
// Wx[i][d] = sum_k x[i][k] * W[d][k], split-precision bf16 (W = Whi + Wlo).
__global__ __launch_bounds__(256) void gemm_wx(const float* __restrict__ X,
                                               const float* __restrict__ W,
                                               float* __restrict__ Co) {
  __shared__ unsigned short As[128][40];
  __shared__ unsigned short Bh[128][40];
  __shared__ unsigned short Bl[128][40];
  const int bn = blockIdx.x & 7;        // d-tile
  const int bm = blockIdx.x >> 3;       // i-tile
  const int tid = threadIdx.x;
  const int wave = tid >> 6, lane = tid & 63, l15 = lane & 15, quad = lane >> 4;
  const int wm = wave & 1, wn = wave >> 1;
  f4v acc[4][4];
  for (int i = 0; i < 4; ++i)
    for (int j = 0; j < 4; ++j) acc[i][j] = (f4v){0.f, 0.f, 0.f, 0.f};
  const int row = tid >> 1, kh = (tid & 1) * 16;
  const float* srcA = X + ((size_t)(bm * 128 + row)) * DIM + kh;
  const float* srcB = W + ((size_t)(bn * 128 + row)) * DIM + kh;
  for (int k0 = 0; k0 < DIM; k0 += 32) {
    __syncthreads();
    unsigned short ta[16], th[16], tl[16];
    for (int q = 0; q < 16; q += 4) {
      f4v a4 = *(const f4v*)(srcA + k0 + q);
      for (int r2 = 0; r2 < 4; ++r2) ta[q + r2] = f2bf(a4[r2]);
      f4v b4 = *(const f4v*)(srcB + k0 + q);
      for (int r2 = 0; r2 < 4; ++r2) {
        unsigned short hi = f2bf(b4[r2]);
        th[q + r2] = hi;
        tl[q + r2] = f2bf(b4[r2] - bf2f(hi));
      }
    }
    *(s8v*)&As[row][kh] = *(s8v*)&ta[0];
    *(s8v*)&As[row][kh + 8] = *(s8v*)&ta[8];
    *(s8v*)&Bh[row][kh] = *(s8v*)&th[0];
    *(s8v*)&Bh[row][kh + 8] = *(s8v*)&th[8];
    *(s8v*)&Bl[row][kh] = *(s8v*)&tl[0];
    *(s8v*)&Bl[row][kh + 8] = *(s8v*)&tl[8];
    __syncthreads();
    s8v af[4], bhf[4], blf[4];
    for (int i = 0; i < 4; ++i) af[i] = *(const s8v*)&As[wm * 64 + i * 16 + l15][quad * 8];
    for (int j = 0; j < 4; ++j) bhf[j] = *(const s8v*)&Bh[wn * 64 + j * 16 + l15][quad * 8];
    for (int j = 0; j < 4; ++j) blf[j] = *(const s8v*)&Bl[wn * 64 + j * 16 + l15][quad * 8];
    for (int i = 0; i < 4; ++i)
      for (int j = 0; j < 4; ++j) {
        acc[i][j] = __builtin_amdgcn_mfma_f32_16x16x32_bf16(af[i], bhf[j], acc[i][j], 0, 0, 0);
        acc[i][j] = __builtin_amdgcn_mfma_f32_16x16x32_bf16(af[i], blf[j], acc[i][j], 0, 0, 0);
      }
  }
  for (int i = 0; i < 4; ++i)
    for (int j = 0; j < 4; ++j) {
      int ci = bm * 128 + wm * 64 + i * 16 + quad * 4;
      int cd = bn * 128 + wn * 64 + j * 16 + l15;
      for (int r2 = 0; r2 < 4; ++r2)
        Co[((size_t)(ci + r2)) * DIM + cd] = acc[i][j][r2];
    }
}

// ----------------------------------------------------------- recurrence ----
// 8 slot-groups x NG WGs. Per WG: register-resident V-slice (16 R-rows) and
// U-slice (64 D-rows) as MFMA A-frags. Two L2-atomic group barriers per step.
__global__ __launch_bounds__(256) void seq_kernel(const float* __restrict__ Wx,
                                                  float* __restrict__ hOut,
                                                  const float* __restrict__ bias,
                                                  const unsigned short* __restrict__ Ub,
                                                  const unsigned short* __restrict__ Vb,
                                                  unsigned short* __restrict__ hx,
                                                  unsigned short* __restrict__ vx,
                                                  unsigned int* __restrict__ cnt) {
  const int s = blockIdx.x & 7;         // slot  (blockIdx%8 -> same XCD per slot, heuristic)
  const int g = blockIdx.x >> 3;        // group member 0..15
  const int tid = threadIdx.x;
  const int wave = tid >> 6, lane = tid & 63, l15 = lane & 15, quad = lane >> 4;
  const int r0 = g * RCH, d0 = g * DCH;

  __shared__ unsigned short hbuf[16][DIM + 8];    // [b][d] bf16 (rows 8..15 unused)
  __shared__ unsigned short vbuf[16][RANK + 8];   // [b][r] bf16
  __shared__ float red[4][16][16];                // stage1 cross-wave reduce

  // persistent weight fragments
  s8v Vfrag[8], Ufrag[8];
  {
    const unsigned short* Vp = Vb + ((size_t)s * RANK + r0 + l15) * DIM + wave * 256 + quad * 8;
    for (int kk = 0; kk < 8; ++kk) Vfrag[kk] = *(const s8v*)(Vp + kk * 32);
    const unsigned short* Up = Ub + ((size_t)s * DIM + d0 + wave * 16 + l15) * RANK + quad * 8;
    for (int kk = 0; kk < 8; ++kk) Ufrag[kk] = *(const s8v*)(Up + kk * 32);
  }
  float bias4[4];
  {
    int db = d0 + wave * 16 + quad * 4;
    for (int r2 = 0; r2 < 4; ++r2) bias4[r2] = bias[db + r2];
  }
  // initial h (= h0) into LDS
  {
    const unsigned short* src = hx + ((size_t)s * 2 + 0) * BB * DIM;
    for (int c = tid; c < 1024; c += 256) {
      int b = c >> 7, off = (c & 127) * 8;
      *(s8v*)&hbuf[b][off] = *(const s8v*)(src + (size_t)b * DIM + off);
    }
  }
  __syncthreads();

  unsigned int* cA = cnt + s;
  unsigned int* cB = cnt + NS + s;

  for (int t = 0; t < TSTEPS; ++t) {
    const int p = t & 1;
    // ---- stage 1: vT[r,b] partial over this wave's K-quarter
    f4v acc = (f4v){0.f, 0.f, 0.f, 0.f};
    {
      const int kbase = wave * 256 + quad * 8;
      for (int kk = 0; kk < 8; ++kk) {
        s8v hfrag = *(const s8v*)&hbuf[l15][kbase + kk * 32];
        acc = __builtin_amdgcn_mfma_f32_16x16x32_bf16(Vfrag[kk], hfrag, acc, 0, 0, 0);
      }
    }
    // hoist Wx load for this step (independent of barrier A)
    const int b_ep = l15;
    const int dbase = d0 + wave * 16 + quad * 4;
    f4v wx4 = (f4v){0.f, 0.f, 0.f, 0.f};
    if (b_ep < 8)
      wx4 = *(const f4v*)&Wx[((size_t)t * BB + b_ep) * DIM + dbase];

    for (int r2 = 0; r2 < 4; ++r2) red[wave][quad * 4 + r2][l15] = acc[r2];
    __syncthreads();
    if (tid < 128) {
      int r = tid >> 3, b = tid & 7;
      float v = red[0][r][b] + red[1][r][b] + red[2][r][b] + red[3][r][b];
      vx[(((size_t)s * 2 + p) * BB + b) * RANK + r0 + r] = f2bf(v);
    }
    __syncthreads();
    // ---- barrier A (v chunks visible)
    if (tid == 0) {
      __hip_atomic_fetch_add(cA, 1u, __ATOMIC_RELEASE, __HIP_MEMORY_SCOPE_AGENT);
      const unsigned tgt = (unsigned)(NG * (t + 1));
      while (__hip_atomic_load(cA, __ATOMIC_RELAXED, __HIP_MEMORY_SCOPE_AGENT) < tgt)
        __builtin_amdgcn_s_sleep(1);
      (void)__hip_atomic_load(cA, __ATOMIC_ACQUIRE, __HIP_MEMORY_SCOPE_AGENT);
    }
    __syncthreads();
    // stage full v -> LDS
    {
      const unsigned short* src = vx + ((size_t)s * 2 + p) * BB * RANK;
      int b = tid >> 5, off = (tid & 31) * 8;
      *(s8v*)&vbuf[b][off] = *(const s8v*)(src + (size_t)b * RANK + off);
    }
    __syncthreads();
    // ---- stage 2: u[d,b] for this WG's D-slice, K = full RANK
    f4v acc2 = (f4v){0.f, 0.f, 0.f, 0.f};
    {
      const int kbase = quad * 8;
      for (int kk = 0; kk < 8; ++kk) {
        s8v vfrag = *(const s8v*)&vbuf[l15][kbase + kk * 32];
        acc2 = __builtin_amdgcn_mfma_f32_16x16x32_bf16(Ufrag[kk], vfrag, acc2, 0, 0, 0);
      }
    }
    if (b_ep < 8) {
      f4v h4;
      s4v hbv;
      for (int r2 = 0; r2 < 4; ++r2) {
        float u = acc2[r2] + wx4[r2] + bias4[r2];
        u = fminf(fmaxf(u, -15.f), 15.f);
        float e = __expf(2.f * u);
        float hv = (e - 1.f) / (e + 1.f);
        h4[r2] = hv;
        hbv[r2] = (short)f2bf(hv);
      }
      *(f4v*)&hOut[(((size_t)(t + 1) * NS + s) * BB + b_ep) * DIM + dbase] = h4;
      *(s4v*)&hx[(((size_t)s * 2 + ((t + 1) & 1)) * BB + b_ep) * DIM + dbase] = hbv;
    }
    __syncthreads();
    // ---- barrier B (h(t+1) visible)
    if (tid == 0) {
      __hip_atomic_fetch_add(cB, 1u, __ATOMIC_RELEASE, __HIP_MEMORY_SCOPE_AGENT);
      const unsigned tgt = (unsigned)(NG * (t + 1));
      while (__hip_atomic_load(cB, __ATOMIC_RELAXED, __HIP_MEMORY_SCOPE_AGENT) < tgt)
        __builtin_amdgcn_s_sleep(1);
      (void)__hip_atomic_load(cB, __ATOMIC_ACQUIRE, __HIP_MEMORY_SCOPE_AGENT);
    }
    __syncthreads();
    // stage h(t+1) -> LDS for next step
    {
      const unsigned short* src = hx + ((size_t)s * 2 + ((t + 1) & 1)) * BB * DIM;
      for (int c = tid; c < 1024; c += 256) {
        int b = c >> 7, off = (c & 127) * 8;
        *(s8v*)&hbuf[b][off] = *(const s8v*)(src + (size_t)b * DIM + off);
      }
    }
    __syncthreads();
  }
}

// ------------------------------------------------------------- epilogue ----
// out[t,b,d] = (sum_s C[s]*h[t+1,s,b,d]) * silu(z[t,b,d])
__global__ void out_kernel(const float* __restrict__ z, const float* __restrict__ h,
                           const float* __restrict__ Cs, float* __restrict__ out) {
  size_t i = (size_t)blockIdx.x * blockDim.x + threadIdx.x;
  const size_t n4 = (size_t)TSTEPS * BB * DIM / 4;
  float c[8];
  for (int s2 = 0; s2 < 8; ++s2) c[s2] = Cs[s2];
  for (; i < n4; i += (size_t)gridDim.x * blockDim.x) {
    size_t base = i * 4;
    size_t t = base / (BB * DIM);
    size_t rem = base % (BB * DIM);
    f4v accv = (f4v){0.f, 0.f, 0.f, 0.f};
    for (int s2 = 0; s2 < 8; ++s2) {
      f4v hv = *(const f4v*)&h[((t + 1) * NS + s2) * (size_t)(BB * DIM) + rem];
      accv += hv * c[s2];
    }
    f4v zv = *(const f4v*)&z[base];
    f4v o;
    for (int r2 = 0; r2 < 4; ++r2) {
      float zz = zv[r2];
      float sil = zz / (1.f + __expf(-zz));
      o[r2] = accv[r2] * sil;
    }
    *(f4v*)&out[base] = o;
  }
}

// ---------------------------------------------------------------- launch ----
extern "C" void kernel_launch(void* const* d_in, const int* in_sizes, int n_in,
                              void* d_out, int out_size, void* d_ws, size_t ws_size,
                              hipStream_t stream) {
  const float* x  = (const float*)d_in[0];   // [T,B,D]
  const float* z  = (const float*)d_in[1];   // [T,B,D]
  const float* h0 = (const float*)d_in[2];   // [B,S,D]
  const float* Wm = (const float*)d_in[3];   // [D,D]
  const float* U  = (const float*)d_in[4];   // [S,D,R]
  const float* V  = (const float*)d_in[5];   // [S,R,D]
  const float* bs = (const float*)d_in[6];   // [D]
  const float* Cs = (const float*)d_in[7];   // [S]

  float* out  = (float*)d_out;                       // [T,B,D]
  float* hOut = out + (size_t)TSTEPS * BB * DIM;     // [T+1,S,B,D]

  unsigned short* Ub = (unsigned short*)d_ws;                    // S*D*R bf16
  unsigned short* Vb = Ub + (size_t)NS * DIM * RANK;             // S*R*D bf16
  unsigned short* hx = Vb + (size_t)NS * DIM * RANK;             // S*2*B*D bf16
  unsigned short* vx = hx + (size_t)NS * 2 * BB * DIM;           // S*2*B*R bf16
  unsigned int* cnt  = (unsigned int*)(vx + (size_t)NS * 2 * BB * RANK);  // 16

  float* Wx = out;  // reuse output region as Wx scratch (overwritten by out_kernel)

  init_kernel<<<2048, 256, 0, stream>>>(U, V, h0, Ub, Vb, hx, hOut, cnt);
  gemm_wx<<<512, 256, 0, stream>>>(x, Wm, Wx);
  seq_kernel<<<128, 256, 0, stream>>>(Wx, hOut, bs, Ub, Vb, hx, vx, cnt);
  out_kernel<<<2048, 256, 0, stream>>>(z, hOut, Cs, out);
}

// Round 2
// 4901.255 us; speedup vs baseline: 2.5982x; 2.5982x over previous
//
#include <hip/hip_runtime.h>
#include <cstdint>
#include <cstddef>

#define DIM 1024
#define NS 8
#define RANK 256
#define TSTEPS 1024
#define BB 8
#define NG 8          // workgroups per slot
#define DCH 128       // DIM / NG : d-slice per WG

typedef __attribute__((ext_vector_type(8))) short s8v;   // 8 x bf16
typedef __attribute__((ext_vector_type(4))) short s4v;   // 4 x bf16
typedef __attribute__((ext_vector_type(4))) float f4v;
typedef __attribute__((ext_vector_type(2))) float f2v;

__device__ __forceinline__ unsigned short f2bf(float f) {
  unsigned u = __float_as_uint(f);
  u += 0x7fffu + ((u >> 16) & 1u);          // round-to-nearest-even
  return (unsigned short)(u >> 16);
}
__device__ __forceinline__ float bf2f(unsigned short h) {
  return __uint_as_float(((unsigned)h) << 16);
}

// ---------------------------------------------------------------- init ----
// Seed hOut[0][s][b][d] = h0[b][s][d]; zero barrier counters.
__global__ void init_kernel(const float* __restrict__ h0, float* __restrict__ hOut0,
                            unsigned int* __restrict__ cnt) {
  int i = blockIdx.x * blockDim.x + threadIdx.x;
  const int NH = NS * BB * DIM;              // 65536
  if (i < NH) {
    int s = i >> 13, b = (i >> 10) & 7, d = i & 1023;
    hOut0[i] = h0[((size_t)b * NS + s) * DIM + d];
  }
  if (i < 128) cnt[i] = 0u;
}

// ---------------------------------------------------------------- GEMM ----
// Wx[i][d] = sum_k x[i][k] * W[d][k], split-precision bf16 (W = Whi + Wlo).
__global__ __launch_bounds__(256) void gemm_wx(const float* __restrict__ X,
                                               const float* __restrict__ W,
                                               float* __restrict__ Co) {
  __shared__ unsigned short As[128][40];
  __shared__ unsigned short Bh[128][40];
  __shared__ unsigned short Bl[128][40];
  const int bn = blockIdx.x & 7;        // d-tile
  const int bm = blockIdx.x >> 3;       // i-tile
  const int tid = threadIdx.x;
  const int wave = tid >> 6, lane = tid & 63, l15 = lane & 15, quad = lane >> 4;
  const int wm = wave & 1, wn = wave >> 1;
  f4v acc[4][4];
  for (int i = 0; i < 4; ++i)
    for (int j = 0; j < 4; ++j) acc[i][j] = (f4v){0.f, 0.f, 0.f, 0.f};
  const int row = tid >> 1, kh = (tid & 1) * 16;
  const float* srcA = X + ((size_t)(bm * 128 + row)) * DIM + kh;
  const float* srcB = W + ((size_t)(bn * 128 + row)) * DIM + kh;
  for (int k0 = 0; k0 < DIM; k0 += 32) {
    __syncthreads();
    unsigned short ta[16], th[16], tl[16];
    for (int q = 0; q < 16; q += 4) {
      f4v a4 = *(const f4v*)(srcA + k0 + q);
      for (int r2 = 0; r2 < 4; ++r2) ta[q + r2] = f2bf(a4[r2]);
      f4v b4 = *(const f4v*)(srcB + k0 + q);
      for (int r2 = 0; r2 < 4; ++r2) {
        unsigned short hi = f2bf(b4[r2]);
        th[q + r2] = hi;
        tl[q + r2] = f2bf(b4[r2] - bf2f(hi));
      }
    }
    *(s8v*)&As[row][kh] = *(s8v*)&ta[0];
    *(s8v*)&As[row][kh + 8] = *(s8v*)&ta[8];
    *(s8v*)&Bh[row][kh] = *(s8v*)&th[0];
    *(s8v*)&Bh[row][kh + 8] = *(s8v*)&th[8];
    *(s8v*)&Bl[row][kh] = *(s8v*)&tl[0];
    *(s8v*)&Bl[row][kh + 8] = *(s8v*)&tl[8];
    __syncthreads();
    s8v af[4], bhf[4], blf[4];
    for (int i = 0; i < 4; ++i) af[i] = *(const s8v*)&As[wm * 64 + i * 16 + l15][quad * 8];
    for (int j = 0; j < 4; ++j) bhf[j] = *(const s8v*)&Bh[wn * 64 + j * 16 + l15][quad * 8];
    for (int j = 0; j < 4; ++j) blf[j] = *(const s8v*)&Bl[wn * 64 + j * 16 + l15][quad * 8];
    for (int i = 0; i < 4; ++i)
      for (int j = 0; j < 4; ++j) {
        acc[i][j] = __builtin_amdgcn_mfma_f32_16x16x32_bf16(af[i], bhf[j], acc[i][j], 0, 0, 0);
        acc[i][j] = __builtin_amdgcn_mfma_f32_16x16x32_bf16(af[i], blf[j], acc[i][j], 0, 0, 0);
      }
  }
  for (int i = 0; i < 4; ++i)
    for (int j = 0; j < 4; ++j) {
      int ci = bm * 128 + wm * 64 + i * 16 + quad * 4;
      int cd = bn * 128 + wn * 64 + j * 16 + l15;
      for (int r2 = 0; r2 < 4; ++r2)
        Co[((size_t)(ci + r2)) * DIM + cd] = acc[i][j][r2];
    }
}

// ----------------------------------------------------------- recurrence ----
// 8 slots x NG WGs. WG g owns d-slice [g*128, g*128+128):
//   stage1: vpart[r,b] = sum_{d in slice} V[s][r][d] * h_loc[d][b]   (local h!)
//   exchange vpart (fp32, relaxed coherent atomics) -- ONE barrier --
//   sum NG partials, stage2: u[d-slice,b] = sum_r U[s][d][r] * v[r,b]
//   h_new d-slice -> LDS (local) + hOut (global, plain streaming stores).
__global__ __launch_bounds__(256) void seq_kernel(const float* __restrict__ Wx,
                                                  float* __restrict__ hOut,
                                                  const float* __restrict__ bias,
                                                  const float* __restrict__ U,
                                                  const float* __restrict__ V,
                                                  const float* __restrict__ h0,
                                                  float* __restrict__ vx,
                                                  unsigned int* __restrict__ cnt) {
  const int s = blockIdx.x & 7;
  const int g = blockIdx.x >> 3;
  const int tid = threadIdx.x;
  const int wave = tid >> 6, lane = tid & 63, l15 = lane & 15, quad = lane >> 4;
  const int d0 = g * DCH;

  __shared__ unsigned short hbuf[16][DCH + 8];    // [b][d_local] bf16 (rows 8..15 junk)
  __shared__ unsigned short vbuf[16][RANK + 8];   // [b][r] bf16 (rows 8..15 junk)

  // ---- persistent weight fragments (fp32 -> bf16), MFMA A-layout ----
  // stage1 A = V rows: m=r, k=d_local. Wave handles 4 M-tiles (64 r), K=128.
  s8v Vfrag[4][4];
  #pragma unroll
  for (int mt = 0; mt < 4; ++mt)
    #pragma unroll
    for (int kk = 0; kk < 4; ++kk) {
      const float* p = V + ((size_t)s * RANK + wave * 64 + mt * 16 + l15) * DIM
                         + d0 + kk * 32 + quad * 8;
      s8v f;
      #pragma unroll
      for (int j = 0; j < 8; ++j) f[j] = (short)f2bf(p[j]);
      Vfrag[mt][kk] = f;
    }
  // stage2 A = U rows: m=d_local, k=r. Wave handles 2 M-tiles (32 d), K=256.
  s8v Ufrag[2][8];
  #pragma unroll
  for (int mt = 0; mt < 2; ++mt)
    #pragma unroll
    for (int kk = 0; kk < 8; ++kk) {
      const float* p = U + ((size_t)s * DIM + d0 + wave * 32 + mt * 16 + l15) * RANK
                         + kk * 32 + quad * 8;
      s8v f;
      #pragma unroll
      for (int j = 0; j < 8; ++j) f[j] = (short)f2bf(p[j]);
      Ufrag[mt][kk] = f;
    }
  float bias4[2][4];
  #pragma unroll
  for (int mt = 0; mt < 2; ++mt)
    #pragma unroll
    for (int r2 = 0; r2 < 4; ++r2)
      bias4[mt][r2] = bias[d0 + wave * 32 + mt * 16 + quad * 4 + r2];

  // seed local h slice from h0
  for (int c = tid; c < BB * DCH; c += 256) {
    int b = c >> 7, dl = c & 127;
    hbuf[b][dl] = f2bf(h0[((size_t)b * NS + s) * DIM + d0 + dl]);
  }
  __syncthreads();

  unsigned int* cA = cnt + s * 16;  // 64B-spaced per-slot counters
  const int b_ep = l15;             // epilogue batch lane

  for (int t = 0; t < TSTEPS; ++t) {
    const int buf = t & 1;
    // ---- stage 1: partial v over local d-slice (K=128, all in-wave)
    f4v acc1[4];
    #pragma unroll
    for (int mt = 0; mt < 4; ++mt) acc1[mt] = (f4v){0.f, 0.f, 0.f, 0.f};
    #pragma unroll
    for (int kk = 0; kk < 4; ++kk) {
      s8v hfrag = *(const s8v*)&hbuf[l15][kk * 32 + quad * 8];
      #pragma unroll
      for (int mt = 0; mt < 4; ++mt)
        acc1[mt] = __builtin_amdgcn_mfma_f32_16x16x32_bf16(Vfrag[mt][kk], hfrag, acc1[mt], 0, 0, 0);
    }
    // prefetch Wx for the epilogue (plain cached loads)
    f4v wx4[2];
    if (b_ep < 8) {
      #pragma unroll
      for (int mt = 0; mt < 2; ++mt)
        wx4[mt] = *(const f4v*)&Wx[((size_t)t * BB + b_ep) * DIM + d0 + wave * 32 + mt * 16 + quad * 4];
    }
    // ---- write partial v: relaxed coherent 8B atomic stores, layout [region][b][r]
    {
      unsigned long long* vw = (unsigned long long*)vx
          + ((size_t)(s * 2 + buf) * NG + g) * 1024 + (size_t)l15 * 128;
      if (l15 < 8) {
        #pragma unroll
        for (int mt = 0; mt < 4; ++mt) {
          int half = wave * 32 + mt * 8 + quad * 2;   // u64 index of r = wave*64+mt*16+quad*4
          union { f2v f; unsigned long long u; } c0, c1;
          c0.f = (f2v){acc1[mt][0], acc1[mt][1]};
          c1.f = (f2v){acc1[mt][2], acc1[mt][3]};
          __hip_atomic_store(vw + half, c0.u, __ATOMIC_RELAXED, __HIP_MEMORY_SCOPE_AGENT);
          __hip_atomic_store(vw + half + 1, c1.u, __ATOMIC_RELAXED, __HIP_MEMORY_SCOPE_AGENT);
        }
      }
    }
    asm volatile("s_waitcnt vmcnt(0)" ::: "memory");  // stores acked at coherent point
    __syncthreads();
    // ---- single barrier: per-slot monotonic counter, no fences
    if (tid == 0) {
      __hip_atomic_fetch_add(cA, 1u, __ATOMIC_RELAXED, __HIP_MEMORY_SCOPE_AGENT);
      const unsigned tgt = (unsigned)(NG * (t + 1));
      while (__hip_atomic_load(cA, __ATOMIC_RELAXED, __HIP_MEMORY_SCOPE_AGENT) < tgt) {}
    }
    __syncthreads();
    // ---- read all NG partials, fp32 sum, bf16 -> LDS vbuf[b][r]
    {
      const int b = tid >> 5, r0 = (tid & 31) * 8;
      const unsigned long long* vr = (const unsigned long long*)vx
          + ((size_t)(s * 2 + buf) * NG) * 1024 + (size_t)b * 128 + (tid & 31) * 4;
      float sum[8] = {0.f, 0.f, 0.f, 0.f, 0.f, 0.f, 0.f, 0.f};
      #pragma unroll
      for (int g2 = 0; g2 < NG; ++g2) {
        #pragma unroll
        for (int q = 0; q < 4; ++q) {
          unsigned long long u = __hip_atomic_load(vr + (size_t)g2 * 1024 + q,
                                                   __ATOMIC_RELAXED, __HIP_MEMORY_SCOPE_AGENT);
          union { unsigned long long u; f2v f; } c; c.u = u;
          sum[q * 2] += c.f[0];
          sum[q * 2 + 1] += c.f[1];
        }
      }
      s8v v8;
      #pragma unroll
      for (int j = 0; j < 8; ++j) v8[j] = (short)f2bf(sum[j]);
      *(s8v*)&vbuf[b][r0] = v8;
    }
    __syncthreads();
    // ---- stage 2: u for local d-slice, K = full RANK
    f4v acc2[2];
    acc2[0] = (f4v){0.f, 0.f, 0.f, 0.f};
    acc2[1] = (f4v){0.f, 0.f, 0.f, 0.f};
    #pragma unroll
    for (int kk = 0; kk < 8; ++kk) {
      s8v vfrag = *(const s8v*)&vbuf[l15][kk * 32 + quad * 8];
      acc2[0] = __builtin_amdgcn_mfma_f32_16x16x32_bf16(Ufrag[0][kk], vfrag, acc2[0], 0, 0, 0);
      acc2[1] = __builtin_amdgcn_mfma_f32_16x16x32_bf16(Ufrag[1][kk], vfrag, acc2[1], 0, 0, 0);
    }
    // ---- epilogue: tanh, write hOut (fp32 global) + local hbuf (bf16)
    if (b_ep < 8) {
      #pragma unroll
      for (int mt = 0; mt < 2; ++mt) {
        int dl = wave * 32 + mt * 16 + quad * 4;
        f4v h4;
        s4v hb;
        #pragma unroll
        for (int r2 = 0; r2 < 4; ++r2) {
          float u = acc2[mt][r2] + wx4[mt][r2] + bias4[mt][r2];
          u = fminf(fmaxf(u, -15.f), 15.f);
          float e = __expf(2.f * u);
          float hv = (e - 1.f) / (e + 1.f);
          h4[r2] = hv;
          hb[r2] = (short)f2bf(hv);
        }
        *(f4v*)&hOut[(((size_t)(t + 1) * NS + s) * BB + b_ep) * DIM + d0 + dl] = h4;
        *(s4v*)&hbuf[b_ep][dl] = hb;
      }
    }
    __syncthreads();  // hbuf(t+1) visible to all waves before next stage1
  }
}

// ------------------------------------------------------------- epilogue ----
__global__ void out_kernel(const float* __restrict__ z, const float* __restrict__ h,
                           const float* __restrict__ Cs, float* __restrict__ out) {
  size_t i = (size_t)blockIdx.x * blockDim.x + threadIdx.x;
  const size_t n4 = (size_t)TSTEPS * BB * DIM / 4;
  float c[8];
  for (int s2 = 0; s2 < 8; ++s2) c[s2] = Cs[s2];
  for (; i < n4; i += (size_t)gridDim.x * blockDim.x) {
    size_t base = i * 4;
    size_t t = base / (BB * DIM);
    size_t rem = base % (BB * DIM);
    f4v accv = (f4v){0.f, 0.f, 0.f, 0.f};
    for (int s2 = 0; s2 < 8; ++s2) {
      f4v hv = *(const f4v*)&h[((t + 1) * NS + s2) * (size_t)(BB * DIM) + rem];
      accv += hv * c[s2];
    }
    f4v zv = *(const f4v*)&z[base];
    f4v o;
    for (int r2 = 0; r2 < 4; ++r2) {
      float zz = zv[r2];
      float sil = zz / (1.f + __expf(-zz));
      o[r2] = accv[r2] * sil;
    }
    *(f4v*)&out[base] = o;
  }
}

// ---------------------------------------------------------------- launch ----
extern "C" void kernel_launch(void* const* d_in, const int* in_sizes, int n_in,
                              void* d_out, int out_size, void* d_ws, size_t ws_size,
                              hipStream_t stream) {
  const float* x  = (const float*)d_in[0];   // [T,B,D]
  const float* z  = (const float*)d_in[1];   // [T,B,D]
  const float* h0 = (const float*)d_in[2];   // [B,S,D]
  const float* Wm = (const float*)d_in[3];   // [D,D]
  const float* U  = (const float*)d_in[4];   // [S,D,R]
  const float* V  = (const float*)d_in[5];   // [S,R,D]
  const float* bs = (const float*)d_in[6];   // [D]
  const float* Cs = (const float*)d_in[7];   // [S]

  float* out  = (float*)d_out;                       // [T,B,D]
  float* hOut = out + (size_t)TSTEPS * BB * DIM;     // [T+1,S,B,D]

  float* vx = (float*)d_ws;                               // S*2*NG*B*R fp32 = 1 MB
  unsigned int* cnt = (unsigned int*)(vx + (size_t)NS * 2 * NG * BB * RANK);  // 128

  float* Wx = out;  // reuse `out` region as Wx scratch (overwritten by out_kernel)

  init_kernel<<<256, 256, 0, stream>>>(h0, hOut, cnt);
  gemm_wx<<<512, 256, 0, stream>>>(x, Wm, Wx);
  seq_kernel<<<64, 256, 0, stream>>>(Wx, hOut, bs, U, V, h0, vx, cnt);
  out_kernel<<<2048, 256, 0, stream>>>(z, hOut, Cs, out);
}